// Round 2
// baseline (251.664 us; speedup 1.0000x reference)
//
#include <hip/hip_runtime.h>

// PatchEmbedding2 on MI355X.
// Pass 1: layout (token -> x base offset + size mask), 1 block.
// Pass 2: gather x patches into dense bf16 A [Mpad x 3072] + convert W -> bf16.
//   Key identity: Wf = W.reshape(E,C,kd,kd,s,s).sum(2,3) acts on the FLAT
//   1024-index f of (32,32): f = a*kd*s^2 + b*s^2 + p*s + q. So the dense
//   A-row is A[c,f] = patch[c, (f>>log2s)&(s-1), f&(s-1)]  (period s^2 in f,
//   row-major s x s inside each chunk) — NOT periodic tiling of the 2-D grid.
// Pass 3: bf16 MFMA GEMM (m97 structure): C[M,768] = A * Wb^T + bias, fp32 out.
// Workspace: 64KB + 4.7MB (Wb) + Mpad*3072*2 (~49.5MB) ~= 55 MB.

typedef __attribute__((ext_vector_type(8))) short bf16x8;
typedef __attribute__((ext_vector_type(4))) float f32x4;

#define K_DIM 3072
#define N_DIM 768

__device__ __forceinline__ unsigned short f2bf(float f) {
  unsigned int u = __float_as_uint(f);
  u += 0x7fffu + ((u >> 16) & 1u);   // RNE
  return (unsigned short)(u >> 16);
}

__device__ __forceinline__ void gload16(const void* g, void* l) {
  __builtin_amdgcn_global_load_lds(
      (const __attribute__((address_space(1))) void*)g,
      (__attribute__((address_space(3))) void*)l, 16, 0, 0);
}

// ---------------- Pass 1: token layout ----------------
__global__ void layout_kernel(const float* __restrict__ iw, int P,
                              int* __restrict__ tokBase, int* __restrict__ tokMask) {
  __shared__ double s_wsum[16];
  __shared__ double s_avg;
  __shared__ int s_cnt[1024];
  int tid = threadIdx.x;
  float v = (tid < P) ? iw[tid] : 0.0f;
  double d = (double)v;
#pragma unroll
  for (int off = 32; off > 0; off >>= 1) d += __shfl_down(d, off, 64);
  if ((tid & 63) == 0) s_wsum[tid >> 6] = d;
  __syncthreads();
  if (tid == 0) {
    double s = 0.0;
    for (int i = 0; i < 16; ++i) s += s_wsum[i];
    s_avg = s / (double)P;
  }
  __syncthreads();
  int cnt = 0, sz = 32;
  if (tid < P) {
    double val = 32.0 * pow(s_avg / (double)v, 0.05);
    if (val > 32.0) val = 32.0;
    // nearest of {32,16,8,4}; ties (24,12,6) go to the larger (np.argmin first index)
    sz = (val >= 24.0) ? 32 : (val >= 12.0) ? 16 : (val >= 6.0) ? 8 : 4;
    cnt = (sz < 32) ? (32 / sz) : 1;
  }
  s_cnt[tid] = cnt;
  __syncthreads();
  for (int dl = 1; dl < 1024; dl <<= 1) {  // Hillis-Steele inclusive scan
    int add = (tid >= dl) ? s_cnt[tid - dl] : 0;
    __syncthreads();
    s_cnt[tid] += add;
    __syncthreads();
  }
  if (tid < P) {
    int off = s_cnt[tid] - cnt;                 // exclusive offset
    int ini_col = (tid * 32) & 1023;            // (i*ps) % H
    int ini_row = (tid * 32 * 32) >> 10;        // (i*ps*ps) / H
    if (sz == 32) {
      tokBase[off] = ini_row * 1024 + ini_col;
      tokMask[off] = 31;
    } else {
      int ns = 32 / sz;                          // ns*sz == 32
      for (int j = 0; j < ns; ++j) {
        int r = ini_row + (j * sz) / ns;
        int c = ini_col + ((j * sz) & 31);
        tokBase[off + j] = r * 1024 + c;
        tokMask[off + j] = sz - 1;
      }
    }
  }
}

// ---------------- Pass 2a: W -> bf16 ----------------
__global__ void wconv_kernel(const float* __restrict__ W, unsigned short* __restrict__ Wb,
                             int total4) {
  int idx = blockIdx.x * blockDim.x + threadIdx.x;
  if (idx >= total4) return;
  float4 f = *(const float4*)(W + (size_t)idx * 4);
  ushort4 o;
  o.x = f2bf(f.x); o.y = f2bf(f.y); o.z = f2bf(f.z); o.w = f2bf(f.w);
  *(ushort4*)(Wb + (size_t)idx * 4) = o;
}

// ---------------- Pass 2b: gather patches -> bf16 A ----------------
__global__ void gather_kernel(const float* __restrict__ x,
                              const int* __restrict__ tokBase,
                              const int* __restrict__ tokMask,
                              unsigned short* __restrict__ Ab,
                              int T, int Mtot, int total4) {
  int idx = blockIdx.x * blockDim.x + threadIdx.x;  // one float4-group of one A row
  if (idx >= total4) return;
  int m = idx / 768;
  int p = (idx - m * 768) * 4;                      // k position 0..3068
  ushort4 o;
  if (m < Mtot) {
    int b = m / T;
    int t = m - b * T;
    int base = tokBase[t];
    int mask = tokMask[t];                          // s-1
    int sh = __popc(mask);                          // log2(s)
    int c = p >> 10;
    int f = p & 1023;                               // flat index within (32,32)
    int h = (f >> sh) & mask;                       // p = (f/s) % s
    int w = f & mask;                               // q = f % s (group of 4 stays contiguous)
    const float* src = x + (size_t)b * 3145728 + (size_t)c * 1048576 +
                       (size_t)base + (size_t)(h * 1024) + (size_t)w;
    float4 fv = *(const float4*)src;                // 16B aligned (col mult 16, w mult 4)
    o.x = f2bf(fv.x); o.y = f2bf(fv.y); o.z = f2bf(fv.z); o.w = f2bf(fv.w);
  } else {
    o = make_ushort4(0, 0, 0, 0);                   // zero-pad rows up to Mpad
  }
  *(ushort4*)(Ab + (size_t)m * K_DIM + p) = o;
}

// ---------------- Pass 3: bf16 GEMM, C = A * Wb^T + bias ----------------
__global__ __launch_bounds__(256, 2)
void gemm_kernel(const unsigned short* __restrict__ A, const unsigned short* __restrict__ Wb,
                 const float* __restrict__ bias, float* __restrict__ out, int Mtot) {
  __shared__ unsigned short Alds[128 * 32];  // 8 KB, row-major, NO padding (global_load_lds)
  __shared__ unsigned short Blds[128 * 32];  // 8 KB
  int tid = threadIdx.x;
  int lane = tid & 63;
  int wave = tid >> 6;           // 0..3
  int wr = wave >> 1, wc = wave & 1;
  int mBase = blockIdx.y * 128;
  int nBase = blockIdx.x * 128;

  f32x4 acc[4][4] = {};

  // staging addressing: wave stages rows [wave*32, wave*32+32) of each tile,
  // two 1KB instructions (16 rows each); lane -> row=lane>>2, 16B chunk=lane&3
  int sr = lane >> 2;
  int sc = lane & 3;
  const unsigned short* Ag0 = A + (size_t)(mBase + wave * 32 + sr) * K_DIM + sc * 8;
  const unsigned short* Ag1 = Ag0 + (size_t)16 * K_DIM;
  const unsigned short* Bg0 = Wb + (size_t)(nBase + wave * 32 + sr) * K_DIM + sc * 8;
  const unsigned short* Bg1 = Bg0 + (size_t)16 * K_DIM;
  unsigned short* Al0 = Alds + wave * 1024 + lane * 8;
  unsigned short* Al1 = Al0 + 512;
  unsigned short* Bl0 = Blds + wave * 1024 + lane * 8;
  unsigned short* Bl1 = Bl0 + 512;

  int rr = lane & 15, q = lane >> 4;

  for (int k0 = 0; k0 < K_DIM; k0 += 32) {
    gload16(Ag0 + k0, Al0);
    gload16(Ag1 + k0, Al1);
    gload16(Bg0 + k0, Bl0);
    gload16(Bg1 + k0, Bl1);
    __syncthreads();

    bf16x8 aF[4], bF[4];
#pragma unroll
    for (int i = 0; i < 4; ++i)
      aF[i] = *(const bf16x8*)&Alds[(wr * 64 + i * 16 + rr) * 32 + q * 8];
#pragma unroll
    for (int j = 0; j < 4; ++j)
      bF[j] = *(const bf16x8*)&Blds[(wc * 64 + j * 16 + rr) * 32 + q * 8];
#pragma unroll
    for (int i = 0; i < 4; ++i)
#pragma unroll
      for (int j = 0; j < 4; ++j)
        acc[i][j] = __builtin_amdgcn_mfma_f32_16x16x32_bf16(aF[i], bF[j], acc[i][j], 0, 0, 0);
    __syncthreads();
  }

  // epilogue: C/D layout col=lane&15, row=(lane>>4)*4+reg
#pragma unroll
  for (int j = 0; j < 4; ++j) {
    int n = nBase + wc * 64 + j * 16 + rr;
    float bv = bias[n];
#pragma unroll
    for (int i = 0; i < 4; ++i) {
      int mrow = mBase + wr * 64 + i * 16 + q * 4;
#pragma unroll
      for (int r2 = 0; r2 < 4; ++r2) {
        int m = mrow + r2;
        if (m < Mtot) out[(size_t)m * N_DIM + n] = acc[i][j][r2] + bv;
      }
    }
  }
}

extern "C" void kernel_launch(void* const* d_in, const int* in_sizes, int n_in,
                              void* d_out, int out_size, void* d_ws, size_t ws_size,
                              hipStream_t stream) {
  const float* x  = (const float*)d_in[0];
  const float* iw = (const float*)d_in[1];
  const float* W  = (const float*)d_in[2];
  const float* b  = (const float*)d_in[3];
  int P = in_sizes[1];                        // 992 patches
  int B = in_sizes[0] / (3 * 1024 * 1024);    // 8
  int E = in_sizes[3];                        // 768
  int T = out_size / (B * E);                 // 995 tokens
  int Mtot = B * T;                           // 7960
  int Mpad = (Mtot + 127) & ~127;             // 8064

  char* ws = (char*)d_ws;
  int* tokBase = (int*)ws;                              // 32 KB
  int* tokMask = (int*)(ws + 32768);                    // 32 KB
  unsigned short* Wb = (unsigned short*)(ws + 65536);   // 768*3072*2 = 4.72 MB
  unsigned short* Ab = (unsigned short*)(ws + 65536 + (size_t)E * K_DIM * 2);

  layout_kernel<<<1, 1024, 0, stream>>>(iw, P, tokBase, tokMask);

  int w4 = E * K_DIM / 4;
  wconv_kernel<<<(w4 + 255) / 256, 256, 0, stream>>>(W, Wb, w4);

  int a4 = Mpad * (K_DIM / 4);
  gather_kernel<<<(a4 + 255) / 256, 256, 0, stream>>>(x, tokBase, tokMask, Ab, T, Mtot, a4);

  dim3 grid(N_DIM / 128, Mpad / 128);
  gemm_kernel<<<grid, 256, 0, stream>>>(Ab, Wb, b, (float*)d_out, Mtot);
}